// Round 2
// baseline (852.138 us; speedup 1.0000x reference)
//
#include <hip/hip_runtime.h>

#define IN_FT   4096
#define OUT_FT  4096
#define B_SZ    256
#define NNZ_T   500000
#define NNZ_N   100000
#define NNZ_TOT 600000
#define QTR     (NNZ_TOT / 4)      // 150000 entries per quarter
#define QTR4    (QTR / 2)          // 75000 uint4 (2 entries each)

// ---- workspace layout (bytes) ----
#define OFF_ENT  0u                // 600000 * 8B packed (rc, val) = 4,800,000
#define OFF_FLAG 4800000u          // 2 i32: idx buffers are int64?

// ---------------------------------------------------------------------------
// out[b][r] = bias[r]  (1M f32 = 256K float4), plus int64-vs-int32 detection
__global__ __launch_bounds__(256) void k_init(const float* __restrict__ bias,
                                              float* __restrict__ out,
                                              const int* __restrict__ st_idx,
                                              const int* __restrict__ sn_idx,
                                              int* __restrict__ flag) {
    int i = blockIdx.x * 256 + threadIdx.x;            // grid = 1024 blocks
    float4* out4 = (float4*)out;
    const float4* bias4 = (const float4*)bias;
    out4[i] = bias4[i & 1023];
    if (blockIdx.x == 0) {
        __shared__ int nz_t, nz_n;
        if (threadIdx.x == 0) { nz_t = 0; nz_n = 0; }
        __syncthreads();
        // if idx is int64, every odd 32-bit word is 0 (values < 4096)
        if (st_idx[2 * threadIdx.x + 1] != 0) atomicAdd(&nz_t, 1);
        if (sn_idx[2 * threadIdx.x + 1] != 0) atomicAdd(&nz_n, 1);
        __syncthreads();
        if (threadIdx.x == 0) { flag[0] = (nz_t == 0); flag[1] = (nz_n == 0); }
    }
}

// ---------------------------------------------------------------------------
__device__ __forceinline__ void get_entry(int i,
                                          const int* __restrict__ st_idx,
                                          const float* __restrict__ st_vals,
                                          const int* __restrict__ sn_idx,
                                          const float* __restrict__ sn_vals,
                                          int stride_t, int stride_n,
                                          int& row, int& col, float& val) {
    if (i < NNZ_T) {
        row = st_idx[(size_t)i * stride_t];
        col = st_idx[(size_t)(NNZ_T + i) * stride_t];
        val = st_vals[i];
    } else {
        int j = i - NNZ_T;
        row = sn_idx[(size_t)j * stride_n];
        col = sn_idx[(size_t)(NNZ_N + j) * stride_n];
        val = sn_vals[j];
    }
}

// pack all nnz into 8B records: (row<<12 | col, val_bits)
__global__ __launch_bounds__(256) void k_pack(const int* __restrict__ st_idx,
                                              const float* __restrict__ st_vals,
                                              const int* __restrict__ sn_idx,
                                              const float* __restrict__ sn_vals,
                                              const int* __restrict__ flag,
                                              uint2* __restrict__ ent) {
    int i = blockIdx.x * 256 + threadIdx.x;
    if (i >= NNZ_TOT) return;
    int s_t = flag[0] ? 2 : 1, s_n = flag[1] ? 2 : 1;
    int row, col; float val;
    get_entry(i, st_idx, st_vals, sn_idx, sn_vals, s_t, s_n, row, col, val);
    ent[i] = make_uint2(((unsigned)row << 12) | (unsigned)col, __float_as_uint(val));
}

// ---------------------------------------------------------------------------
// 256 blocks x 1024 threads. Block (bg, qi): batch rows 4bg..4bg+3,
// entry quarter qi. LDS: xs[4096] float4 (64KB) + acc[4096][4] f32 (64KB).
// qi = blockIdx & 3 so each XCD (round-robin %8) streams ONE 1.2MB quarter.
__global__ __launch_bounds__(1024) void k_spmm3(const float* __restrict__ x,
                                                const uint2* __restrict__ ent,
                                                float* __restrict__ out) {
    extern __shared__ char smem[];
    float4* xs  = (float4*)smem;              // xs[c] = x[4bg+0..3][c]
    float*  xsf = (float*)smem;
    float*  acc = (float*)(smem + 65536);     // acc[r*4 + bsub]
    const int qi = blockIdx.x & 3;
    const int bg = blockIdx.x >> 2;
    const int t  = threadIdx.x;

    #pragma unroll
    for (int b4 = 0; b4 < 4; ++b4) {
        const float* xrow = x + (size_t)(bg * 4 + b4) * IN_FT;
        #pragma unroll
        for (int k = 0; k < IN_FT / 1024; ++k) {
            int c = t + k * 1024;
            xsf[c * 4 + b4] = xrow[c];
        }
    }
    #pragma unroll
    for (int k = 0; k < 16384 / 1024; ++k) acc[t + k * 1024] = 0.f;
    __syncthreads();

    const uint4* ep = (const uint4*)(ent + (size_t)qi * QTR);   // 75000 uint4
    for (int i = t; i < QTR4; i += 2048) {
        uint4 a = ep[i];
        int j = i + 1024;
        uint4 b = make_uint4(0u, 0u, 0u, 0u);
        bool hasb = (j < QTR4);
        if (hasb) b = ep[j];

        {   // entry a0
            float v = __uint_as_float(a.y);
            float4 xv = xs[a.x & 4095u];
            int rb = (int)(a.x >> 12) << 2;
            atomicAdd(&acc[rb + 0], v * xv.x);
            atomicAdd(&acc[rb + 1], v * xv.y);
            atomicAdd(&acc[rb + 2], v * xv.z);
            atomicAdd(&acc[rb + 3], v * xv.w);
        }
        {   // entry a1
            float v = __uint_as_float(a.w);
            float4 xv = xs[a.z & 4095u];
            int rb = (int)(a.z >> 12) << 2;
            atomicAdd(&acc[rb + 0], v * xv.x);
            atomicAdd(&acc[rb + 1], v * xv.y);
            atomicAdd(&acc[rb + 2], v * xv.z);
            atomicAdd(&acc[rb + 3], v * xv.w);
        }
        if (hasb) {
            {   // entry b0
                float v = __uint_as_float(b.y);
                float4 xv = xs[b.x & 4095u];
                int rb = (int)(b.x >> 12) << 2;
                atomicAdd(&acc[rb + 0], v * xv.x);
                atomicAdd(&acc[rb + 1], v * xv.y);
                atomicAdd(&acc[rb + 2], v * xv.z);
                atomicAdd(&acc[rb + 3], v * xv.w);
            }
            {   // entry b1
                float v = __uint_as_float(b.w);
                float4 xv = xs[b.z & 4095u];
                int rb = (int)(b.z >> 12) << 2;
                atomicAdd(&acc[rb + 0], v * xv.x);
                atomicAdd(&acc[rb + 1], v * xv.y);
                atomicAdd(&acc[rb + 2], v * xv.z);
                atomicAdd(&acc[rb + 3], v * xv.w);
            }
        }
    }
    __syncthreads();

    // flush: out[4bg+bsub][r] += acc[r][bsub]  (out pre-filled with bias)
    #pragma unroll
    for (int bsub = 0; bsub < 4; ++bsub) {
        float* orow = out + (size_t)(bg * 4 + bsub) * OUT_FT;
        #pragma unroll
        for (int k = 0; k < OUT_FT / 1024; ++k) {
            int r = t + k * 1024;
            unsafeAtomicAdd(&orow[r], acc[r * 4 + bsub]);
        }
    }
}

// ---------------------------------------------------------------------------
extern "C" void kernel_launch(void* const* d_in, const int* in_sizes, int n_in,
                              void* d_out, int out_size, void* d_ws, size_t ws_size,
                              hipStream_t stream) {
    const float* x       = (const float*)d_in[0];
    const int*   st_idx  = (const int*)d_in[1];
    const float* st_vals = (const float*)d_in[2];
    const int*   sn_idx  = (const int*)d_in[3];
    const float* sn_vals = (const float*)d_in[4];
    const float* bias    = (const float*)d_in[5];
    float* out = (float*)d_out;

    char* ws = (char*)d_ws;
    uint2* ent  = (uint2*)(ws + OFF_ENT);
    int*   flag = (int*)  (ws + OFF_FLAG);

    // allow 128KB dynamic LDS (not a stream op; safe under graph capture)
    static bool attr_done = false;
    (void)hipFuncSetAttribute((const void*)k_spmm3,
                              hipFuncAttributeMaxDynamicSharedMemorySize, 131072);
    (void)attr_done;

    k_init<<<(B_SZ * OUT_FT / 4) / 256, 256, 0, stream>>>(bias, out, st_idx, sn_idx, flag);
    k_pack<<<(NNZ_TOT + 255) / 256, 256, 0, stream>>>(st_idx, st_vals, sn_idx, sn_vals,
                                                      flag, ent);
    k_spmm3<<<256, 1024, 131072, stream>>>(x, ent, out);
}